// Round 1
// baseline (163.074 us; speedup 1.0000x reference)
//
#include <hip/hip_runtime.h>
#include <hip/hip_bf16.h>

#define IN_F   4096
#define OUT_F  4096
#define QBLK   8
#define NBLKS  512     // IN_F / QBLK
#define NTOK   1024

typedef unsigned int u32;
typedef unsigned short u16;
typedef __attribute__((ext_vector_type(8))) short short8;   // 8 bf16 = 4 VGPRs (MFMA A/B frag)
typedef __attribute__((ext_vector_type(4))) float floatx4;  // MFMA C/D frag

// round-to-nearest-even fp32 -> bf16
__device__ __forceinline__ u16 f2bf(float f) {
  union { float f; u32 u; } v; v.f = f;
  u32 u = v.u;
  return (u16)((u + 0x7fffu + ((u >> 16) & 1u)) >> 16);
}

__device__ __forceinline__ void load_lds_16(const void* g, void* l) {
  // async global->LDS, 16B per lane. LDS dest must be wave-uniform base + lane*16.
  __builtin_amdgcn_global_load_lds(
      (const __attribute__((address_space(1))) u32*)g,
      (__attribute__((address_space(3))) u32*)l, 16, 0, 0);
}

// ---------------------------------------------------------------------------
// Kernel 1: expand w = centroids[assignments] into bf16 [OUT_F][IN_F] (B^T layout)
// assignments is block-major: idx = assignments[blk*OUT_F + out]
// Tile 64 out x 64 blk through LDS so both the assignment reads (contiguous in
// out) and the w writes (contiguous in blk -> 16B chunks) are coalesced.
// ---------------------------------------------------------------------------
__global__ __launch_bounds__(256) void expand_w_kernel(
    const int* __restrict__ assign, const float* __restrict__ cent,
    u16* __restrict__ w) {
  __shared__ int tile[64 * 65];   // [blk_local][out_local], pad 65 kills bank conflicts
  const int t = threadIdx.x;
  const int out0 = blockIdx.x * 64;
  const int blk0 = blockIdx.y * 64;

#pragma unroll
  for (int it = 0; it < 16; ++it) {
    int li = it * 256 + t;
    int ol = li & 63;        // fastest: coalesced read of assignments
    int bl = li >> 6;
    tile[bl * 65 + ol] = assign[(size_t)(blk0 + bl) * OUT_F + out0 + ol];
  }
  __syncthreads();

  const float4* cv = (const float4*)cent;
#pragma unroll
  for (int it = 0; it < 16; ++it) {
    int li = it * 256 + t;
    int bl = li & 63;        // fastest: coalesced 16B writes of w
    int ol = li >> 6;
    int idx = tile[bl * 65 + ol];
    float4 c0 = cv[(size_t)idx * 2];
    float4 c1 = cv[(size_t)idx * 2 + 1];
    union { u16 s[8]; uint4 v; } o;
    o.s[0] = f2bf(c0.x); o.s[1] = f2bf(c0.y); o.s[2] = f2bf(c0.z); o.s[3] = f2bf(c0.w);
    o.s[4] = f2bf(c1.x); o.s[5] = f2bf(c1.y); o.s[6] = f2bf(c1.z); o.s[7] = f2bf(c1.w);
    // w[out][blk*8 .. blk*8+7] as one 16B chunk
    ((uint4*)w)[(size_t)(out0 + ol) * (IN_F / 8) + (blk0 + bl)] = o.v;
  }
}

// ---------------------------------------------------------------------------
// Kernel 2: cast x fp32 [NTOK][IN_F] -> bf16
// ---------------------------------------------------------------------------
__global__ __launch_bounds__(256) void cast_x_kernel(
    const float* __restrict__ x, u16* __restrict__ xb) {
  int g = blockIdx.x * 256 + threadIdx.x;   // one 8-element chunk
  const float4* xv = (const float4*)x;
  float4 a = xv[(size_t)g * 2];
  float4 b = xv[(size_t)g * 2 + 1];
  union { u16 s[8]; uint4 v; } o;
  o.s[0] = f2bf(a.x); o.s[1] = f2bf(a.y); o.s[2] = f2bf(a.z); o.s[3] = f2bf(a.w);
  o.s[4] = f2bf(b.x); o.s[5] = f2bf(b.y); o.s[6] = f2bf(b.z); o.s[7] = f2bf(b.w);
  ((uint4*)xb)[g] = o.v;
}

// ---------------------------------------------------------------------------
// Kernel 3: GEMM  C[M][N] = A[M][K] * B[N][K]^T + bias   (m97 structure)
// 128x128 tile, BK=32, 256 threads = 4 waves in 2x2, each wave 64x64 (4x4
// mfma_f32_16x16x32_bf16 tiles). global_load_lds width-16 staging.
// ---------------------------------------------------------------------------
#define BM 128
#define BN 128
#define BK 32

__global__ __launch_bounds__(256) void gemm_bt_kernel(
    const u16* __restrict__ A,   // [NTOK][IN_F] bf16
    const u16* __restrict__ B,   // [OUT_F][IN_F] bf16 (w)
    const float* __restrict__ bias,
    float* __restrict__ C) {     // [NTOK][OUT_F] fp32
  __shared__ __align__(16) u16 As[BM * BK];   // 8 KB, row-major [128][32], no pad
  __shared__ __align__(16) u16 Bs[BN * BK];   // 8 KB

  const int t = threadIdx.x;
  const int lane = t & 63;
  const int wv = t >> 6;
  const int wm = wv >> 1;          // wave row (0..1)
  const int wn = wv & 1;           // wave col (0..1)
  const int quad = lane >> 4;
  const int r16 = lane & 15;
  const int m0 = blockIdx.y * BM;
  const int n0 = blockIdx.x * BN;

  floatx4 acc[4][4];
#pragma unroll
  for (int i = 0; i < 4; ++i)
#pragma unroll
    for (int j = 0; j < 4; ++j)
#pragma unroll
      for (int r = 0; r < 4; ++r) acc[i][j][r] = 0.0f;

  for (int kt = 0; kt < IN_F / BK; ++kt) {
    const int k0 = kt * BK;
    // stage: 512 chunks of 16B per tile; 256 threads x 2 chunks each.
    // chunk c = i*256 + t satisfies (wave-uniform base + lane*16) in LDS.
#pragma unroll
    for (int i = 0; i < 2; ++i) {
      int c = i * 256 + t;
      int row = c >> 2;           // 4 chunks per 64B row
      int c4 = c & 3;
      load_lds_16(A + (size_t)(m0 + row) * IN_F + k0 + c4 * 8, &As[c * 8]);
      load_lds_16(B + (size_t)(n0 + row) * IN_F + k0 + c4 * 8, &Bs[c * 8]);
    }
    __syncthreads();   // drains vmcnt before barrier

    const short8* Asv = (const short8*)As;
    const short8* Bsv = (const short8*)Bs;
    short8 af[4], bf[4];
#pragma unroll
    for (int i = 0; i < 4; ++i)
      af[i] = Asv[(wm * 64 + i * 16 + r16) * 4 + quad];  // A[m=r16][k=quad*8+j]
#pragma unroll
    for (int j = 0; j < 4; ++j)
      bf[j] = Bsv[(wn * 64 + j * 16 + r16) * 4 + quad];  // B[n=r16][k=quad*8+j]

#pragma unroll
    for (int i = 0; i < 4; ++i)
#pragma unroll
      for (int j = 0; j < 4; ++j)
        acc[i][j] = __builtin_amdgcn_mfma_f32_16x16x32_bf16(af[i], bf[j], acc[i][j], 0, 0, 0);

    __syncthreads();   // protect LDS from next iteration's staging
  }

  // epilogue: C/D layout col = lane&15, row = quad*4 + reg
  const int col_base = n0 + wn * 64 + r16;
  const int row_base = m0 + wm * 64 + quad * 4;
#pragma unroll
  for (int j = 0; j < 4; ++j) {
    const int col = col_base + j * 16;
    const float bv = bias[col];
#pragma unroll
    for (int i = 0; i < 4; ++i) {
      const int row = row_base + i * 16;
#pragma unroll
      for (int r = 0; r < 4; ++r)
        C[(size_t)(row + r) * OUT_F + col] = acc[i][j][r] + bv;
    }
  }
}

extern "C" void kernel_launch(void* const* d_in, const int* in_sizes, int n_in,
                              void* d_out, int out_size, void* d_ws, size_t ws_size,
                              hipStream_t stream) {
  const float* x      = (const float*)d_in[0];  // [1024][4096] fp32
  const float* cent   = (const float*)d_in[1];  // [2048][8] fp32
  const float* bias   = (const float*)d_in[2];  // [4096] fp32
  const int*   assign = (const int*)d_in[3];    // [512*4096] int32, block-major
  // d_in[4] = counts, unused in forward
  float* out = (float*)d_out;                   // [1024][4096] fp32

  // workspace layout: w bf16 (32 MB) | xb bf16 (8 MB)
  u16* w  = (u16*)d_ws;
  u16* xb = (u16*)((char*)d_ws + (size_t)OUT_F * IN_F * sizeof(u16));

  hipLaunchKernelGGL(expand_w_kernel, dim3(OUT_F / 64, NBLKS / 64), dim3(256), 0, stream,
                     assign, cent, w);
  hipLaunchKernelGGL(cast_x_kernel, dim3((NTOK * IN_F / 8) / 256), dim3(256), 0, stream,
                     x, xb);
  hipLaunchKernelGGL(gemm_bt_kernel, dim3(OUT_F / BN, NTOK / BM), dim3(256), 0, stream,
                     xb, w, bias, out);
}

// Round 2
// 131.663 us; speedup vs baseline: 1.2386x; 1.2386x over previous
//
#include <hip/hip_runtime.h>
#include <hip/hip_bf16.h>

#define IN_F   4096
#define OUT_F  4096
#define QBLK   8
#define NBLKS  512
#define NTOK   1024
#define NCENT  2048

typedef unsigned int u32;
typedef unsigned short u16;
typedef __attribute__((ext_vector_type(8))) short short8;   // 8 bf16 (MFMA A/B frag)
typedef __attribute__((ext_vector_type(4))) float floatx4;  // MFMA C/D frag

// round-to-nearest-even fp32 -> bf16
__device__ __forceinline__ u16 f2bf(float f) {
  union { float f; u32 u; } v; v.f = f;
  u32 u = v.u;
  return (u16)((u + 0x7fffu + ((u >> 16) & 1u)) >> 16);
}

__device__ __forceinline__ void load_lds_16(const void* g, void* l) {
  __builtin_amdgcn_global_load_lds(
      (const __attribute__((address_space(1))) u32*)g,
      (__attribute__((address_space(3))) u32*)l, 16, 0, 0);
}

// ---------------------------------------------------------------------------
// cast fp32 -> bf16, 8 elems per thread (used for x and for centroids)
// ---------------------------------------------------------------------------
__global__ __launch_bounds__(256) void cast_bf16_kernel(
    const float* __restrict__ src, u16* __restrict__ dst) {
  int g = blockIdx.x * 256 + threadIdx.x;   // one 8-element chunk
  const float4* sv = (const float4*)src;
  float4 a = sv[(size_t)g * 2];
  float4 b = sv[(size_t)g * 2 + 1];
  union { u16 s[8]; uint4 v; } o;
  o.s[0] = f2bf(a.x); o.s[1] = f2bf(a.y); o.s[2] = f2bf(a.z); o.s[3] = f2bf(a.w);
  o.s[4] = f2bf(b.x); o.s[5] = f2bf(b.y); o.s[6] = f2bf(b.z); o.s[7] = f2bf(b.w);
  ((uint4*)dst)[g] = o.v;
}

// ---------------------------------------------------------------------------
// Fused GEMM: C[m][n] = sum_k x[m][k] * centroids[assign[(k/8)*OUT_F+n]][k%8]
// Block tile 128x128, 4 waves (2x2) each 64x64 (4x4 of mfma_f32_16x16x32_bf16).
// B fragments gathered directly from bf16 centroid table in LDS (one 16B
// lookup per lane per frag: lane (n=r16, quad) needs exactly quant-block
// kblk = k0/8 + quad). Split-K over gridDim.z; s=0 -> d_out, s>0 -> partials.
// As uses XOR swizzle (k-quad ^= row&3) to kill the 8-way bank conflict of
// the unpadded [128][32] layout (padding breaks global_load_lds).
// ---------------------------------------------------------------------------
__global__ __launch_bounds__(256, 4) void gemm_fused_kernel(
    const u16* __restrict__ A,      // xb [NTOK][IN_F] bf16
    const u16* __restrict__ centb,  // [NCENT][8] bf16
    const int* __restrict__ assign, // [NBLKS*OUT_F] block-major
    const float* __restrict__ bias,
    float* __restrict__ out0,       // d_out (chunk s=0)
    float* __restrict__ partials) { // (S-1) x [NTOK][OUT_F]
  __shared__ __align__(16) u16 cs[NCENT * 8];   // 32 KB centroid table
  __shared__ __align__(16) u16 As[128 * 32];    // 8 KB, swizzled

  const int t = threadIdx.x;
  const int lane = t & 63;
  const int wv = t >> 6;
  const int wm = wv >> 1;
  const int wn = wv & 1;
  const int quad = lane >> 4;
  const int r16 = lane & 15;
  const int m0 = blockIdx.y * 128;
  const int n0 = blockIdx.x * 128;
  const int s = blockIdx.z;
  const int kchunk = IN_F / gridDim.z;
  const int k_base = s * kchunk;
  const int iters = kchunk / 32;

  // stage centroid table: 2048 chunks of 16B = 8 per thread
#pragma unroll
  for (int it = 0; it < 8; ++it) {
    int c = it * 256 + t;
    load_lds_16(centb + (size_t)c * 8, cs + (size_t)c * 8);
  }

  floatx4 acc[4][4];
#pragma unroll
  for (int i = 0; i < 4; ++i)
#pragma unroll
    for (int j = 0; j < 4; ++j)
#pragma unroll
      for (int r = 0; r < 4; ++r) acc[i][j][r] = 0.0f;

  const int ncol = n0 + wn * 64 + r16;
  const int sq = quad ^ (r16 & 3);   // read-side swizzle (row&3 == r16&3)

  for (int kt = 0; kt < iters; ++kt) {
    const int k0 = k_base + kt * 32;

    // B indices: quant-block kb = k0/8 + quad, column ncol + j*16
    int idxv[4];
    const int kb = (k0 >> 3) + quad;
#pragma unroll
    for (int j = 0; j < 4; ++j)
      idxv[j] = assign[(size_t)kb * OUT_F + ncol + j * 16];

    // stage A (8 KB = 512 chunks, 2 per thread), XOR-swizzled k-quad
#pragma unroll
    for (int i = 0; i < 2; ++i) {
      int p = i * 256 + t;
      int row = p >> 2;
      int q = (p & 3) ^ (row & 3);
      load_lds_16(A + (size_t)(m0 + row) * IN_F + k0 + q * 8, As + p * 8);
    }
    __syncthreads();   // drains centroid DMA (iter 0) + A DMA

    const short8* Asv = (const short8*)As;
    const short8* csv = (const short8*)cs;
    short8 af[4], bfr[4];
#pragma unroll
    for (int i = 0; i < 4; ++i)
      af[i] = Asv[(wm * 64 + i * 16 + r16) * 4 + sq];
#pragma unroll
    for (int j = 0; j < 4; ++j)
      bfr[j] = csv[idxv[j]];

#pragma unroll
    for (int i = 0; i < 4; ++i)
#pragma unroll
      for (int j = 0; j < 4; ++j)
        acc[i][j] = __builtin_amdgcn_mfma_f32_16x16x32_bf16(af[i], bfr[j], acc[i][j], 0, 0, 0);

    __syncthreads();   // protect As from next iteration's staging
  }

  // epilogue: C/D layout col = lane&15 (+j*16), row = quad*4 + reg (+i*16)
  float* C = (s == 0) ? out0 : (partials + (size_t)(s - 1) * NTOK * OUT_F);
  const bool add_bias = (gridDim.z == 1);   // no reduce pass in S=1 fallback
  const int row_base = m0 + wm * 64 + quad * 4;
#pragma unroll
  for (int j = 0; j < 4; ++j) {
    const int col = ncol + j * 16;
    const float bv = add_bias ? bias[col] : 0.0f;
#pragma unroll
    for (int i = 0; i < 4; ++i) {
      const int row = row_base + i * 16;
#pragma unroll
      for (int r = 0; r < 4; ++r)
        C[(size_t)(row + r) * OUT_F + col] = acc[i][j][r] + bv;
    }
  }
}

// ---------------------------------------------------------------------------
// reduce: out += sum(partials) + bias   (float4 per thread)
// ---------------------------------------------------------------------------
__global__ __launch_bounds__(256) void reduce_kernel(
    float* __restrict__ out, const float* __restrict__ partials,
    const float* __restrict__ bias, int sm1) {
  int g = blockIdx.x * 256 + threadIdx.x;  // float4 index over [NTOK*OUT_F/4]
  float4 v = ((const float4*)out)[g];
  for (int s = 0; s < sm1; ++s) {
    float4 p = ((const float4*)(partials + (size_t)s * NTOK * OUT_F))[g];
    v.x += p.x; v.y += p.y; v.z += p.z; v.w += p.w;
  }
  float4 b = ((const float4*)bias)[g & (OUT_F / 4 - 1)];
  v.x += b.x; v.y += b.y; v.z += b.z; v.w += b.w;
  ((float4*)out)[g] = v;
}

extern "C" void kernel_launch(void* const* d_in, const int* in_sizes, int n_in,
                              void* d_out, int out_size, void* d_ws, size_t ws_size,
                              hipStream_t stream) {
  const float* x      = (const float*)d_in[0];  // [1024][4096] fp32
  const float* cent   = (const float*)d_in[1];  // [2048][8] fp32
  const float* bias   = (const float*)d_in[2];  // [4096] fp32
  const int*   assign = (const int*)d_in[3];    // [512*4096] int32
  float* out = (float*)d_out;

  // ws layout: xb (8 MB) | centb (32 KB) | partials (S-1)*16 MB
  const size_t xb_bytes   = (size_t)NTOK * IN_F * sizeof(u16);      // 8388608
  const size_t cent_bytes = (size_t)NCENT * 8 * sizeof(u16);        // 32768
  const size_t part_bytes = (size_t)NTOK * OUT_F * sizeof(float);   // 16777216
  u16*   xb       = (u16*)d_ws;
  u16*   centb    = (u16*)((char*)d_ws + xb_bytes);
  float* partials = (float*)((char*)d_ws + xb_bytes + cent_bytes);

  const size_t base = xb_bytes + cent_bytes;
  int S = 1;
  if (ws_size >= base + 3 * part_bytes) S = 4;
  else if (ws_size >= base + 1 * part_bytes) S = 2;

  hipLaunchKernelGGL(cast_bf16_kernel, dim3((NTOK * IN_F / 8) / 256), dim3(256), 0, stream,
                     x, xb);
  hipLaunchKernelGGL(cast_bf16_kernel, dim3((NCENT * 8 / 8) / 256), dim3(256), 0, stream,
                     cent, centb);
  hipLaunchKernelGGL(gemm_fused_kernel, dim3(OUT_F / 128, NTOK / 128, S), dim3(256), 0, stream,
                     xb, centb, assign, bias, out, partials);
  if (S > 1)
    hipLaunchKernelGGL(reduce_kernel, dim3((NTOK * OUT_F / 4) / 256), dim3(256), 0, stream,
                       out, partials, bias, S - 1);
}